// Round 1
// baseline (50.413 us; speedup 1.0000x reference)
//
#include <hip/hip_runtime.h>
#include <hip/hip_bf16.h>

#define ALPHA 0.25f
#define DELTA 0.5f

// ---------------------------------------------------------------------------
// Kernel 1: grid-stride elementwise loss + hierarchical reduction to one
// partial sum per block (written to d_ws as float). float4 loads = 16B/lane.
// ---------------------------------------------------------------------------
__global__ void __launch_bounds__(256)
dafl_partial_kernel(const float* __restrict__ y_pred,
                    const float* __restrict__ y_true,
                    float* __restrict__ partials,
                    long long n4)   // number of float4 elements
{
    const float4* __restrict__ p4 = reinterpret_cast<const float4*>(y_pred);
    const float4* __restrict__ t4 = reinterpret_cast<const float4*>(y_true);

    float acc = 0.0f;
    long long idx = (long long)blockIdx.x * blockDim.x + threadIdx.x;
    long long stride = (long long)gridDim.x * blockDim.x;

    for (long long i = idx; i < n4; i += stride) {
        float4 p = p4[i];
        float4 t = t4[i];

        #pragma unroll
        for (int j = 0; j < 4; ++j) {
            float pp = (&p.x)[j];
            float tt = (&t.x)[j];

            // class weight: lut[clip(round(t),0,3)] with round-half-to-even
            float r = rintf(tt);                       // v_rndne_f32, matches jnp.round
            r = fminf(fmaxf(r, 0.0f), 3.0f);
            int cls = (int)r;
            float w = (cls == 0) ? 1.0f
                    : (cls == 1) ? 4.0f
                    : (cls == 2) ? 3.0f
                    :              2.0f;

            float d = fabsf(pp - tt);
            // focal: clip(d/0.5, 0, 1)^2  (d >= 0 so lower clip is free)
            float f = fminf(d * 2.0f, 1.0f);
            f = f * f;
            // smooth-L1 with beta=0.5: d<0.5 ? 0.5*d*d/0.5 : d - 0.25
            float base = (d < DELTA) ? (d * d) : (d - 0.25f);

            acc += ALPHA * f * base * w;
        }
    }

    // wave-level reduction (64 lanes)
    #pragma unroll
    for (int off = 32; off > 0; off >>= 1)
        acc += __shfl_down(acc, off, 64);

    // block-level: 256 threads = 4 waves
    __shared__ float smem[4];
    int lane = threadIdx.x & 63;
    int wave = threadIdx.x >> 6;
    if (lane == 0) smem[wave] = acc;
    __syncthreads();

    if (threadIdx.x == 0) {
        float s = smem[0] + smem[1] + smem[2] + smem[3];
        partials[blockIdx.x] = s;
    }
}

// ---------------------------------------------------------------------------
// Kernel 2: reduce the per-block partials and write the mean. One block.
// ---------------------------------------------------------------------------
__global__ void __launch_bounds__(256)
dafl_final_kernel(const float* __restrict__ partials,
                  float* __restrict__ out,
                  int num_partials,
                  float inv_n)
{
    float acc = 0.0f;
    for (int i = threadIdx.x; i < num_partials; i += 256)
        acc += partials[i];

    #pragma unroll
    for (int off = 32; off > 0; off >>= 1)
        acc += __shfl_down(acc, off, 64);

    __shared__ float smem[4];
    int lane = threadIdx.x & 63;
    int wave = threadIdx.x >> 6;
    if (lane == 0) smem[wave] = acc;
    __syncthreads();

    if (threadIdx.x == 0) {
        float s = smem[0] + smem[1] + smem[2] + smem[3];
        out[0] = s * inv_n;
    }
}

extern "C" void kernel_launch(void* const* d_in, const int* in_sizes, int n_in,
                              void* d_out, int out_size, void* d_ws, size_t ws_size,
                              hipStream_t stream) {
    const float* y_pred = (const float*)d_in[0];
    const float* y_true = (const float*)d_in[1];
    float* out = (float*)d_out;
    float* partials = (float*)d_ws;

    long long n = (long long)in_sizes[0];       // total elements (B*N)
    long long n4 = n >> 2;                      // float4 count (n divisible by 4)

    const int BLOCK = 256;
    const int GRID  = 2048;                     // 256 CUs * 8 blocks/CU

    dafl_partial_kernel<<<GRID, BLOCK, 0, stream>>>(y_pred, y_true, partials, n4);
    dafl_final_kernel<<<1, BLOCK, 0, stream>>>(partials, out, GRID,
                                               1.0f / (double)n);
}